// Round 4
// baseline (157.762 us; speedup 1.0000x reference)
//
#include <hip/hip_runtime.h>

#define FDIM 256
#define H1D  256
#define H2D  128
#define BATCH 4096
#define BM   128
#define FPB  8
#define NBT  (BATCH / BM)   // 32 batch tiles
#define NFG  (FDIM / FPB)   // 32 feature groups

typedef _Float16 half8 __attribute__((ext_vector_type(8)));
typedef float    f32x4 __attribute__((ext_vector_type(4)));

// ---------------------------------------------------------------------------
// Prep: W2 (F,H1,H2) fp32 -> f16 MFMA B-fragment-linear layout in ws.
// Fragment (f, s, t): k = 32s + kpat(g,j), n = 16t + (lane&15),
// kpat(g,j) = 4g + j (j<4) | 16 + 4g + (j-4) (j>=4), g = lane>>4.
// ---------------------------------------------------------------------------
__global__ __launch_bounds__(512) void prep_w2(const float* __restrict__ W2,
                                               _Float16* __restrict__ w2f) {
    const int f    = blockIdx.x >> 3;
    const int s    = blockIdx.x & 7;
    const int t    = threadIdx.x >> 6;
    const int lane = threadIdx.x & 63;
    const int g    = lane >> 4;
    const int ln   = lane & 15;
    const int n    = t * 16 + ln;
    half8 v;
#pragma unroll
    for (int j = 0; j < 8; ++j) {
        const int k = s * 32 + 4 * g + (j < 4 ? j : 12 + j);
        v[j] = (_Float16)W2[(f * H1D + k) * H2D + n];
    }
    *(half8*)(w2f + (size_t)(((f * 8 + s) * 8 + t) * 64 + lane) * 8) = v;
}

// ---------------------------------------------------------------------------
// Main: 4-wave blocks (256 thr), BM=128 batch rows, wave w owns n-cols
// [32w, 32w+32). k-chunk (32-wide) double-buffered h1 in LDS; per chunk:
// load 2 B frags (global, L2-resident w2f), stage next chunk (wave-uniform
// W1/b1 scalar loads + VALU -> swizzled ds_write, split across 4 waves),
// 8x2 MFMA on current chunk, one barrier. N=32/wave keeps acc at 64 regs ->
// no spills. Epilogue folds relu(.+b2).W3 into sacc per feature.
// ---------------------------------------------------------------------------
__global__ __launch_bounds__(256, 3) void coxnam_main(
    const float* __restrict__ x,  const float* __restrict__ W1,
    const float* __restrict__ b1, const float* __restrict__ b2,
    const float* __restrict__ W3, const _Float16* __restrict__ w2f,
    float* __restrict__ partial) {
    __shared__ _Float16 h1[2][BM * 32];   // 2 x 8 KB
    __shared__ float red[4][BM];          // 2 KB

    const int t    = threadIdx.x;
    const int w    = t >> 6;
    const int lane = t & 63;
    const int g    = lane >> 4;
    const int ln   = lane & 15;
    const int row  = t & 127;             // staging row this thread owns
    // XCD-aware bijective swizzle (grid 1024 = 8*128): fg-contiguous per XCD
    const int wg = (blockIdx.x & 7) * 128 + (blockIdx.x >> 3);
    const int fg = wg >> 5, bt = wg & 31, b0 = bt * BM;

    f32x4 acc[8][2];
    float sacc[8][4];
#pragma unroll
    for (int mi = 0; mi < 8; ++mi) {
#pragma unroll
        for (int qt = 0; qt < 2; ++qt) acc[mi][qt] = (f32x4){0.f, 0.f, 0.f, 0.f};
#pragma unroll
        for (int r = 0; r < 4; ++r) sacc[mi][r] = 0.f;
    }

    // stage one 32-k chunk of layer 1 into h1[buf]; thread t owns row t&127,
    // two 8-k slots (by t>>7). slot swizzle gq^((row>>1)&3): conflict-free.
    auto stage = [&](int f, int s, int buf, float xv) {
        const int gq0 = (t >> 7) * 2;
        const float* w1p = W1 + f * H1D + s * 32;
        const float* b1p = b1 + f * H1D + s * 32;
        char* base = (char*)&h1[buf][0] + row * 64;
#pragma unroll
        for (int q = 0; q < 2; ++q) {
            const int gq = gq0 + q;
            const float4 wlo = *(const float4*)(w1p + 4 * gq);
            const float4 whi = *(const float4*)(w1p + 16 + 4 * gq);
            const float4 blo = *(const float4*)(b1p + 4 * gq);
            const float4 bhi = *(const float4*)(b1p + 16 + 4 * gq);
            half8 hv;
            hv[0] = (_Float16)fmaxf(fmaf(xv, wlo.x, blo.x), 0.f);
            hv[1] = (_Float16)fmaxf(fmaf(xv, wlo.y, blo.y), 0.f);
            hv[2] = (_Float16)fmaxf(fmaf(xv, wlo.z, blo.z), 0.f);
            hv[3] = (_Float16)fmaxf(fmaf(xv, wlo.w, blo.w), 0.f);
            hv[4] = (_Float16)fmaxf(fmaf(xv, whi.x, bhi.x), 0.f);
            hv[5] = (_Float16)fmaxf(fmaf(xv, whi.y, bhi.y), 0.f);
            hv[6] = (_Float16)fmaxf(fmaf(xv, whi.z, bhi.z), 0.f);
            hv[7] = (_Float16)fmaxf(fmaf(xv, whi.w, bhi.w), 0.f);
            const int slot = gq ^ ((row >> 1) & 3);
            *(half8*)(base + slot * 16) = hv;
        }
    };

    float xcur = x[(size_t)(b0 + row) * FDIM + fg * FPB];
    stage(fg * FPB, 0, 0, xcur);
    __syncthreads();

    for (int fi = 0; fi < FPB; ++fi) {
        const int f = fg * FPB + fi;
        const float xnext =
            (fi + 1 < FPB) ? x[(size_t)(b0 + row) * FDIM + f + 1] : 0.f;
#pragma unroll
        for (int s = 0; s < 8; ++s) {
            const int buf = s & 1;
            // B fragments for this chunk (global, L2-resident w2f)
            const _Float16* bp =
                w2f + ((size_t)(f * 8 + s) * 8 + 2 * w) * 512 + lane * 8;
            half8 bf[2];
            bf[0] = *(const half8*)(bp);
            bf[1] = *(const half8*)(bp + 512);
            // stage next chunk into the other buffer (overlaps B latency)
            if (s < 7)
                stage(f, s + 1, buf ^ 1, xcur);
            else if (fi + 1 < FPB)
                stage(f + 1, 0, buf ^ 1, xnext);
            // A fragments from LDS + MFMA
            const char* abase = (const char*)&h1[buf][0] + ln * 64 +
                                ((g ^ ((ln >> 1) & 3)) * 16);
#pragma unroll
            for (int mi = 0; mi < 8; ++mi) {
                const half8 af = *(const half8*)(abase + mi * 1024);
                acc[mi][0] = __builtin_amdgcn_mfma_f32_16x16x32_f16(
                    af, bf[0], acc[mi][0], 0, 0, 0);
                acc[mi][1] = __builtin_amdgcn_mfma_f32_16x16x32_f16(
                    af, bf[1], acc[mi][1], 0, 0, 0);
            }
            __syncthreads();
        }
        // ---- epilogue: relu(acc + b2) . W3 -> sacc; reset acc ----
        const int nbase = f * H2D + w * 32 + ln;
        const float b2v0 = b2[nbase], b2v1 = b2[nbase + 16];
        const float w3v0 = W3[nbase], w3v1 = W3[nbase + 16];
#pragma unroll
        for (int mi = 0; mi < 8; ++mi)
#pragma unroll
            for (int r = 0; r < 4; ++r) {
                const float va = fmaxf(acc[mi][0][r] + b2v0, 0.f);
                const float vb = fmaxf(acc[mi][1][r] + b2v1, 0.f);
                sacc[mi][r] = fmaf(va, w3v0, fmaf(vb, w3v1, sacc[mi][r]));
                acc[mi][0][r] = 0.f;
                acc[mi][1][r] = 0.f;
            }
        xcur = xnext;
    }

    // ---- reduce over the 16 n-lanes of each group, then across 4 waves ----
#pragma unroll
    for (int mi = 0; mi < 8; ++mi)
#pragma unroll
        for (int r = 0; r < 4; ++r) {
            float v = sacc[mi][r];
            v += __shfl_xor(v, 1, 16);
            v += __shfl_xor(v, 2, 16);
            v += __shfl_xor(v, 4, 16);
            v += __shfl_xor(v, 8, 16);
            if (ln == 0) red[w][mi * 16 + g * 4 + r] = v;
        }
    __syncthreads();
    if (t < BM)
        partial[(size_t)fg * BATCH + b0 + t] =
            red[0][t] + red[1][t] + red[2][t] + red[3][t];
}

// ---------------------------------------------------------------------------
// Final reduction over feature groups + sum of b3.
// ---------------------------------------------------------------------------
__global__ __launch_bounds__(256) void reduce_out(const float* __restrict__ partial,
                                                  const float* __restrict__ b3,
                                                  float* __restrict__ out) {
    const int b = blockIdx.x * 256 + threadIdx.x;
    float v = 0.f;
#pragma unroll
    for (int fgi = 0; fgi < NFG; ++fgi) v += partial[fgi * BATCH + b];
    float sb3 = 0.f;
#pragma unroll 4
    for (int f4 = 0; f4 < FDIM; f4 += 4) {
        const float4 t = *(const float4*)(b3 + f4);
        sb3 += t.x + t.y + t.z + t.w;
    }
    out[b] = v + sb3;
}

extern "C" void kernel_launch(void* const* d_in, const int* in_sizes, int n_in,
                              void* d_out, int out_size, void* d_ws, size_t ws_size,
                              hipStream_t stream) {
    const float* x  = (const float*)d_in[0];
    const float* W1 = (const float*)d_in[1];
    const float* b1 = (const float*)d_in[2];
    const float* W2 = (const float*)d_in[3];
    const float* b2 = (const float*)d_in[4];
    const float* W3 = (const float*)d_in[5];
    const float* b3 = (const float*)d_in[6];

    const size_t w2f_elems = (size_t)FDIM * H1D * H2D;   // 16 MB f16
    _Float16* w2f  = (_Float16*)d_ws;
    float* partial = (float*)((char*)d_ws + w2f_elems * sizeof(_Float16));
    if (ws_size < w2f_elems * sizeof(_Float16) + (size_t)NFG * BATCH * sizeof(float))
        return;

    prep_w2<<<FDIM * 8, 512, 0, stream>>>(W2, w2f);
    coxnam_main<<<NFG * NBT, 256, 0, stream>>>(x, W1, b1, b2, W3, w2f, partial);
    reduce_out<<<BATCH / 256, 256, 0, stream>>>(partial, b3, (float*)d_out);
}

// Round 5
// 110.841 us; speedup vs baseline: 1.4233x; 1.4233x over previous
//
#include <hip/hip_runtime.h>

#define FDIM  256
#define H1D   256
#define H2D   128
#define BATCH 4096
#define NPART 64

typedef _Float16 half8 __attribute__((ext_vector_type(8)));
typedef float    f32x4 __attribute__((ext_vector_type(4)));

#define W2F_HALVES  ((size_t)FDIM * H1D * H2D)   // 8388608  (16.78 MB)
#define XH_HALVES   ((size_t)FDIM * BATCH)       // 1048576  (2 MB)
#define W1B1_HALVES ((size_t)FDIM * 8 * 4 * 16)  // 131072   (0.25 MB)

// ---------------------------------------------------------------------------
// prep_all: three independent jobs branched on blockIdx.
//  [0,2048):   W2 (f32) -> w2f f16 B-fragments, k-perm kpat(g,j)=4g+j / 16+4g+(j-4)
//  [2048,2304): x (B,F) f32 -> xh (F,B) f16 transpose via LDS tile
//  [2304,2336): W1,b1 -> w1b1 f16 packed per (f,s,g): 8 W1 halves + 8 b1 halves,
//               SAME kpat sigma as w2f (A/B K-map consistency).
// ---------------------------------------------------------------------------
__global__ __launch_bounds__(256) void prep_all(
    const float* __restrict__ x,  const float* __restrict__ W1,
    const float* __restrict__ b1, const float* __restrict__ W2,
    _Float16* __restrict__ w2f, _Float16* __restrict__ xh,
    _Float16* __restrict__ w1b1) {
    __shared__ _Float16 tile[64][66];
    const int tid = threadIdx.x;
    const int bid = blockIdx.x;
    if (bid < 2048) {
        const int f = bid >> 3, s = bid & 7;
        const int lane = tid & 63, g = lane >> 4, ln = lane & 15;
        const int w = tid >> 6;
#pragma unroll
        for (int h = 0; h < 2; ++h) {
            const int tq = w * 2 + h;
            half8 v;
#pragma unroll
            for (int j = 0; j < 8; ++j) {
                const int k = s * 32 + 4 * g + (j < 4 ? j : 12 + j);
                v[j] = (_Float16)W2[(size_t)(f * H1D + k) * H2D + tq * 16 + ln];
            }
            *(half8*)(w2f + (((size_t)(f * 8 + s) * 8 + tq) * 64 + lane) * 8) = v;
        }
    } else if (bid < 2304) {
        const int idx = bid - 2048;
        const int bt = idx >> 2, ft = idx & 3;
        const int tr = tid >> 2;          // 0..63: batch row within tile
        const int c0 = (tid & 3) * 16;    // feature col chunk
#pragma unroll
        for (int j = 0; j < 4; ++j) {
            const float4 v = *(const float4*)(
                x + (size_t)(bt * 64 + tr) * FDIM + ft * 64 + c0 + j * 4);
            tile[tr][c0 + j * 4 + 0] = (_Float16)v.x;
            tile[tr][c0 + j * 4 + 1] = (_Float16)v.y;
            tile[tr][c0 + j * 4 + 2] = (_Float16)v.z;
            tile[tr][c0 + j * 4 + 3] = (_Float16)v.w;
        }
        __syncthreads();
        const int fr = tid >> 2;          // feature row 0..63
        const int bb = (tid & 3) * 16;    // batch chunk
        half8 o0, o1;
#pragma unroll
        for (int i = 0; i < 8; ++i) o0[i] = tile[bb + i][fr];
#pragma unroll
        for (int i = 0; i < 8; ++i) o1[i] = tile[bb + 8 + i][fr];
        _Float16* dst = xh + (size_t)(ft * 64 + fr) * BATCH + bt * 64 + bb;
        *(half8*)dst = o0;
        *(half8*)(dst + 8) = o1;
    } else {
        const int idx = (bid - 2304) * 256 + tid;   // 0..8191
        const int f = idx >> 5, s = (idx >> 2) & 7, g = idx & 3;
        const float4 wlo = *(const float4*)(W1 + f * H1D + s * 32 + 4 * g);
        const float4 whi = *(const float4*)(W1 + f * H1D + s * 32 + 16 + 4 * g);
        const float4 blo = *(const float4*)(b1 + f * H1D + s * 32 + 4 * g);
        const float4 bhi = *(const float4*)(b1 + f * H1D + s * 32 + 16 + 4 * g);
        half8 wv, bv;
        wv[0] = (_Float16)wlo.x; wv[1] = (_Float16)wlo.y;
        wv[2] = (_Float16)wlo.z; wv[3] = (_Float16)wlo.w;
        wv[4] = (_Float16)whi.x; wv[5] = (_Float16)whi.y;
        wv[6] = (_Float16)whi.z; wv[7] = (_Float16)whi.w;
        bv[0] = (_Float16)blo.x; bv[1] = (_Float16)blo.y;
        bv[2] = (_Float16)blo.z; bv[3] = (_Float16)blo.w;
        bv[4] = (_Float16)bhi.x; bv[5] = (_Float16)bhi.y;
        bv[6] = (_Float16)bhi.z; bv[7] = (_Float16)bhi.w;
        _Float16* dst = w1b1 + (size_t)((f * 8 + s) * 4 + g) * 16;
        *(half8*)dst = wv;
        *(half8*)(dst + 8) = bv;
    }
}

// ---------------------------------------------------------------------------
// Main: one independent wave per block (64 thr). No LDS, no barriers.
// Wave = (fsplit: 8 features, bt: 64 batch rows, ns: 64 n-cols).
// Per k-chunk: A-fragment recomputed in registers via packed f16 math
// (4 v_pk_fma + 4 v_pk_max), B fragments from L2-resident w2f, 16 MFMA.
// Epilogue folds relu(.+b2).W3 into sacc per feature. XCD-major mapping
// keeps each XCD's w2f slice (2 MB) L2-resident.
// ---------------------------------------------------------------------------
__global__ __launch_bounds__(64, 3) void coxnam_main(
    const _Float16* __restrict__ xh,  const _Float16* __restrict__ w1b1,
    const _Float16* __restrict__ w2f, const float* __restrict__ b2,
    const float* __restrict__ W3,     float* __restrict__ partial) {
    const int lane = threadIdx.x;
    const int g = lane >> 4, ln = lane & 15;
    const int wid = blockIdx.x;
    const int xcd = wid & 7;
    const int r_  = wid >> 3;                 // 0..511
    const int fsplit = (xcd << 2) | (r_ & 3); // 0..31
    const int u  = r_ >> 2;                   // 0..127
    const int bt = u >> 1, ns = u & 1;
    const int b0 = bt * 64, n0 = ns * 64, f0 = fsplit * 8;

    f32x4 acc[4][4];
    float sacc[4][4];
#pragma unroll
    for (int mi = 0; mi < 4; ++mi)
#pragma unroll
        for (int nt = 0; nt < 4; ++nt) {
            acc[mi][nt] = (f32x4){0.f, 0.f, 0.f, 0.f};
            sacc[mi][nt] = 0.f;
        }

    for (int fi = 0; fi < 8; ++fi) {
        const int f = f0 + fi;
        _Float16 xs[4];
#pragma unroll
        for (int mi = 0; mi < 4; ++mi)
            xs[mi] = xh[(size_t)f * BATCH + b0 + mi * 16 + ln];
#pragma unroll
        for (int s = 0; s < 8; ++s) {
            const _Float16* wb = w1b1 + (size_t)((f * 8 + s) * 4 + g) * 16;
            const half8 w1v = *(const half8*)wb;
            const half8 b1v = *(const half8*)(wb + 8);
            const _Float16* bp =
                w2f + ((size_t)(f * 8 + s) * 8 + ns * 4) * 512 + lane * 8;
            half8 bf[4];
#pragma unroll
            for (int nt = 0; nt < 4; ++nt)
                bf[nt] = *(const half8*)(bp + (size_t)nt * 512);
#pragma unroll
            for (int mi = 0; mi < 4; ++mi) {
                const half8 t = xs[mi] * w1v + b1v;
                const half8 af =
                    __builtin_elementwise_max(t, (half8)(_Float16)0.0f);
#pragma unroll
                for (int nt = 0; nt < 4; ++nt)
                    acc[mi][nt] = __builtin_amdgcn_mfma_f32_16x16x32_f16(
                        af, bf[nt], acc[mi][nt], 0, 0, 0);
            }
        }
        // ---- epilogue: relu(acc + b2) . W3 -> sacc; reset acc ----
        float b2v[4], w3v[4];
#pragma unroll
        for (int nt = 0; nt < 4; ++nt) {
            b2v[nt] = b2[f * H2D + n0 + nt * 16 + ln];
            w3v[nt] = W3[f * H2D + n0 + nt * 16 + ln];
        }
#pragma unroll
        for (int mi = 0; mi < 4; ++mi)
#pragma unroll
            for (int nt = 0; nt < 4; ++nt)
#pragma unroll
                for (int r = 0; r < 4; ++r) {
                    const float v = fmaxf(acc[mi][nt][r] + b2v[nt], 0.f);
                    sacc[mi][r] = fmaf(v, w3v[nt], sacc[mi][r]);
                    acc[mi][nt][r] = 0.f;
                }
    }

    // ---- reduce over the 16 n-lanes within each 4-lane-group row set ----
#pragma unroll
    for (int mi = 0; mi < 4; ++mi)
#pragma unroll
        for (int r = 0; r < 4; ++r) {
            float v = sacc[mi][r];
            v += __shfl_xor(v, 1, 16);
            v += __shfl_xor(v, 2, 16);
            v += __shfl_xor(v, 4, 16);
            v += __shfl_xor(v, 8, 16);
            sacc[mi][r] = v;
        }
    if (ln == 0) {
        float* dst = partial + (size_t)(fsplit * 2 + ns) * BATCH + b0;
#pragma unroll
        for (int mi = 0; mi < 4; ++mi) {
            f32x4 o = {sacc[mi][0], sacc[mi][1], sacc[mi][2], sacc[mi][3]};
            *(f32x4*)(dst + mi * 16 + g * 4) = o;
        }
    }
}

// ---------------------------------------------------------------------------
// Final reduction over 64 partials + sum of b3.
// ---------------------------------------------------------------------------
__global__ __launch_bounds__(256) void reduce_out(const float* __restrict__ partial,
                                                  const float* __restrict__ b3,
                                                  float* __restrict__ out) {
    const int b = blockIdx.x * 256 + threadIdx.x;
    float v = 0.f;
#pragma unroll
    for (int p = 0; p < NPART; ++p) v += partial[(size_t)p * BATCH + b];
    float sb3 = 0.f;
#pragma unroll 4
    for (int f4 = 0; f4 < FDIM; f4 += 4) {
        const float4 t = *(const float4*)(b3 + f4);
        sb3 += t.x + t.y + t.z + t.w;
    }
    out[b] = v + sb3;
}

extern "C" void kernel_launch(void* const* d_in, const int* in_sizes, int n_in,
                              void* d_out, int out_size, void* d_ws, size_t ws_size,
                              hipStream_t stream) {
    const float* x  = (const float*)d_in[0];
    const float* W1 = (const float*)d_in[1];
    const float* b1 = (const float*)d_in[2];
    const float* W2 = (const float*)d_in[3];
    const float* b2 = (const float*)d_in[4];
    const float* W3 = (const float*)d_in[5];
    const float* b3 = (const float*)d_in[6];

    _Float16* w2f  = (_Float16*)d_ws;
    _Float16* xh   = w2f + W2F_HALVES;
    _Float16* w1b1 = xh + XH_HALVES;
    float* partial = (float*)(w1b1 + W1B1_HALVES);
    const size_t need = (W2F_HALVES + XH_HALVES + W1B1_HALVES) * sizeof(_Float16) +
                        (size_t)NPART * BATCH * sizeof(float);
    if (ws_size < need) return;  // insufficient scratch; fail visibly

    prep_all<<<2336, 256, 0, stream>>>(x, W1, b1, W2, w2f, xh, w1b1);
    coxnam_main<<<4096, 64, 0, stream>>>(xh, w1b1, w2f, b2, W3, partial);
    reduce_out<<<BATCH / 256, 256, 0, stream>>>(partial, b3, (float*)d_out);
}

// Round 6
// 90.481 us; speedup vs baseline: 1.7436x; 1.2250x over previous
//
#include <hip/hip_runtime.h>

#define FDIM  256
#define H1D   256
#define H2D   128
#define BATCH 4096
#define NPART 64

typedef _Float16 half8 __attribute__((ext_vector_type(8)));
typedef float    f32x4 __attribute__((ext_vector_type(4)));

#define W2F_HALVES  ((size_t)FDIM * H1D * H2D)   // 8388608  (16.78 MB)
#define XH_HALVES   ((size_t)FDIM * BATCH)       // 1048576  (2 MB)
#define W1B1_HALVES ((size_t)FDIM * 8 * 4 * 16)  // 131072   (0.25 MB)

// ---------------------------------------------------------------------------
// prep_all: three independent jobs branched on blockIdx.
//  [0,2048):   W2 (f32) -> w2f f16 B-fragments, k-perm kpat(g,j)=4g+j / 16+4g+(j-4)
//  [2048,2304): x (B,F) f32 -> xh (F,B) f16 transpose via LDS tile
//  [2304,2336): W1,b1 -> w1b1 f16 packed per (f,s,g): 8 W1 halves + 8 b1 halves,
//               SAME kpat sigma as w2f (A/B K-map consistency).
// ---------------------------------------------------------------------------
__global__ __launch_bounds__(256) void prep_all(
    const float* __restrict__ x,  const float* __restrict__ W1,
    const float* __restrict__ b1, const float* __restrict__ W2,
    _Float16* __restrict__ w2f, _Float16* __restrict__ xh,
    _Float16* __restrict__ w1b1) {
    __shared__ _Float16 tile[64][66];
    const int tid = threadIdx.x;
    const int bid = blockIdx.x;
    if (bid < 2048) {
        const int f = bid >> 3, s = bid & 7;
        const int lane = tid & 63, g = lane >> 4, ln = lane & 15;
        const int w = tid >> 6;
#pragma unroll
        for (int h = 0; h < 2; ++h) {
            const int tq = w * 2 + h;
            half8 v;
#pragma unroll
            for (int j = 0; j < 8; ++j) {
                const int k = s * 32 + 4 * g + (j < 4 ? j : 12 + j);
                v[j] = (_Float16)W2[(size_t)(f * H1D + k) * H2D + tq * 16 + ln];
            }
            *(half8*)(w2f + (((size_t)(f * 8 + s) * 8 + tq) * 64 + lane) * 8) = v;
        }
    } else if (bid < 2304) {
        const int idx = bid - 2048;
        const int bt = idx >> 2, ft = idx & 3;
        const int tr = tid >> 2;          // 0..63: batch row within tile
        const int c0 = (tid & 3) * 16;    // feature col chunk
#pragma unroll
        for (int j = 0; j < 4; ++j) {
            const float4 v = *(const float4*)(
                x + (size_t)(bt * 64 + tr) * FDIM + ft * 64 + c0 + j * 4);
            tile[tr][c0 + j * 4 + 0] = (_Float16)v.x;
            tile[tr][c0 + j * 4 + 1] = (_Float16)v.y;
            tile[tr][c0 + j * 4 + 2] = (_Float16)v.z;
            tile[tr][c0 + j * 4 + 3] = (_Float16)v.w;
        }
        __syncthreads();
        const int fr = tid >> 2;          // feature row 0..63
        const int bb = (tid & 3) * 16;    // batch chunk
        half8 o0, o1;
#pragma unroll
        for (int i = 0; i < 8; ++i) o0[i] = tile[bb + i][fr];
#pragma unroll
        for (int i = 0; i < 8; ++i) o1[i] = tile[bb + 8 + i][fr];
        _Float16* dst = xh + (size_t)(ft * 64 + fr) * BATCH + bt * 64 + bb;
        *(half8*)dst = o0;
        *(half8*)(dst + 8) = o1;
    } else {
        const int idx = (bid - 2304) * 256 + tid;   // 0..8191
        const int f = idx >> 5, s = (idx >> 2) & 7, g = idx & 3;
        const float4 wlo = *(const float4*)(W1 + f * H1D + s * 32 + 4 * g);
        const float4 whi = *(const float4*)(W1 + f * H1D + s * 32 + 16 + 4 * g);
        const float4 blo = *(const float4*)(b1 + f * H1D + s * 32 + 4 * g);
        const float4 bhi = *(const float4*)(b1 + f * H1D + s * 32 + 16 + 4 * g);
        half8 wv, bv;
        wv[0] = (_Float16)wlo.x; wv[1] = (_Float16)wlo.y;
        wv[2] = (_Float16)wlo.z; wv[3] = (_Float16)wlo.w;
        wv[4] = (_Float16)whi.x; wv[5] = (_Float16)whi.y;
        wv[6] = (_Float16)whi.z; wv[7] = (_Float16)whi.w;
        bv[0] = (_Float16)blo.x; bv[1] = (_Float16)blo.y;
        bv[2] = (_Float16)blo.z; bv[3] = (_Float16)blo.w;
        bv[4] = (_Float16)bhi.x; bv[5] = (_Float16)bhi.y;
        bv[6] = (_Float16)bhi.z; bv[7] = (_Float16)bhi.w;
        _Float16* dst = w1b1 + (size_t)((f * 8 + s) * 4 + g) * 16;
        *(half8*)dst = wv;
        *(half8*)(dst + 8) = bv;
    }
}

// ---------------------------------------------------------------------------
// Main: 256-thr blocks = 4 independent waves (no LDS, no barriers) sharing
// the SAME (fsplit, ns) -> identical w2f/w1b1 load streams (L1 broadcast,
// ~4x L2 traffic cut) but different batch tiles (b0 = (btg*4+w)*64).
// Per k-chunk: A-frag recomputed in regs (4 v_pk_fma + 4 v_pk_max), B frags
// double-buffered (compile-time s&1 in unrolled loop), 16 MFMA. b2/W3/x
// prefetched one feature ahead. XCD-major mapping keeps each XCD's 2 MB w2f
// slice L2-resident.
// ---------------------------------------------------------------------------
__global__ __launch_bounds__(256, 3) void coxnam_main(
    const _Float16* __restrict__ xh,  const _Float16* __restrict__ w1b1,
    const _Float16* __restrict__ w2f, const float* __restrict__ b2,
    const float* __restrict__ W3,     float* __restrict__ partial) {
    const int t    = threadIdx.x;
    const int w    = t >> 6;
    const int lane = t & 63;
    const int g = lane >> 4, ln = lane & 15;
    const int bid = blockIdx.x;               // 0..1023
    const int xcd = bid & 7;
    const int r_  = bid >> 3;                 // 0..127
    const int fsplit = (xcd << 2) | (r_ & 3); // 0..31
    const int u   = r_ >> 2;                  // 0..31
    const int ns  = u & 1, btg = u >> 1;      // btg 0..15
    const int b0  = (btg * 4 + w) * 64;
    const int n0  = ns * 64, f0 = fsplit * 8;

    f32x4 acc[4][4];
    float sacc[4][4];
#pragma unroll
    for (int mi = 0; mi < 4; ++mi)
#pragma unroll
        for (int nt = 0; nt < 4; ++nt) {
            acc[mi][nt] = (f32x4){0.f, 0.f, 0.f, 0.f};
            sacc[mi][nt] = 0.f;
        }

    half8 bfb[2][4], wvb[2], bvb[2];
    _Float16 xs[4], xsn[4];

    // prologue: load (f0, s=0) B/W1 frags and first x slice
    {
        const _Float16* bp = w2f + ((size_t)(f0 * 8) * 8 + ns * 4) * 512 + lane * 8;
#pragma unroll
        for (int nt = 0; nt < 4; ++nt) bfb[0][nt] = *(const half8*)(bp + (size_t)nt * 512);
        const _Float16* wb = w1b1 + ((size_t)(f0 * 8) * 4 + g) * 16;
        wvb[0] = *(const half8*)wb;
        bvb[0] = *(const half8*)(wb + 8);
#pragma unroll
        for (int mi = 0; mi < 4; ++mi)
            xs[mi] = xh[(size_t)f0 * BATCH + b0 + mi * 16 + ln];
    }

    for (int fi = 0; fi < 8; ++fi) {
        const int f = f0 + fi;
        // prefetch epilogue constants + next feature's x slice (far ahead)
        float b2v[4], w3v[4];
#pragma unroll
        for (int nt = 0; nt < 4; ++nt) {
            b2v[nt] = b2[f * H2D + n0 + nt * 16 + ln];
            w3v[nt] = W3[f * H2D + n0 + nt * 16 + ln];
        }
        if (fi < 7) {
#pragma unroll
            for (int mi = 0; mi < 4; ++mi)
                xsn[mi] = xh[(size_t)(f + 1) * BATCH + b0 + mi * 16 + ln];
        }
#pragma unroll
        for (int s = 0; s < 8; ++s) {
            const int cur = s & 1, nxt = cur ^ 1;   // compile-time (unrolled)
            // prefetch next chunk's B/W1 fragments
            if (s < 7) {
                const _Float16* bp =
                    w2f + ((size_t)(f * 8 + s + 1) * 8 + ns * 4) * 512 + lane * 8;
#pragma unroll
                for (int nt = 0; nt < 4; ++nt)
                    bfb[nxt][nt] = *(const half8*)(bp + (size_t)nt * 512);
                const _Float16* wb = w1b1 + ((size_t)(f * 8 + s + 1) * 4 + g) * 16;
                wvb[nxt] = *(const half8*)wb;
                bvb[nxt] = *(const half8*)(wb + 8);
            } else if (fi < 7) {
                const _Float16* bp =
                    w2f + ((size_t)(f + 1) * 8 * 8 + ns * 4) * 512 + lane * 8;
#pragma unroll
                for (int nt = 0; nt < 4; ++nt)
                    bfb[nxt][nt] = *(const half8*)(bp + (size_t)nt * 512);
                const _Float16* wb = w1b1 + ((size_t)(f + 1) * 8 * 4 + g) * 16;
                wvb[nxt] = *(const half8*)wb;
                bvb[nxt] = *(const half8*)(wb + 8);
            }
            // compute on current chunk
#pragma unroll
            for (int mi = 0; mi < 4; ++mi) {
                const half8 tt = xs[mi] * wvb[cur] + bvb[cur];
                const half8 af =
                    __builtin_elementwise_max(tt, (half8)(_Float16)0.0f);
#pragma unroll
                for (int nt = 0; nt < 4; ++nt)
                    acc[mi][nt] = __builtin_amdgcn_mfma_f32_16x16x32_f16(
                        af, bfb[cur][nt], acc[mi][nt], 0, 0, 0);
            }
        }
        // ---- epilogue: relu(acc + b2) . W3 -> sacc; reset acc ----
#pragma unroll
        for (int mi = 0; mi < 4; ++mi)
#pragma unroll
            for (int nt = 0; nt < 4; ++nt)
#pragma unroll
                for (int r = 0; r < 4; ++r) {
                    const float v = fmaxf(acc[mi][nt][r] + b2v[nt], 0.f);
                    sacc[mi][r] = fmaf(v, w3v[nt], sacc[mi][r]);
                    acc[mi][nt][r] = 0.f;
                }
#pragma unroll
        for (int mi = 0; mi < 4; ++mi) xs[mi] = xsn[mi];
    }

    // ---- reduce over the 16 n-lanes ----
#pragma unroll
    for (int mi = 0; mi < 4; ++mi)
#pragma unroll
        for (int r = 0; r < 4; ++r) {
            float v = sacc[mi][r];
            v += __shfl_xor(v, 1, 16);
            v += __shfl_xor(v, 2, 16);
            v += __shfl_xor(v, 4, 16);
            v += __shfl_xor(v, 8, 16);
            sacc[mi][r] = v;
        }
    if (ln == 0) {
        float* dst = partial + (size_t)(fsplit * 2 + ns) * BATCH + b0;
#pragma unroll
        for (int mi = 0; mi < 4; ++mi) {
            f32x4 o = {sacc[mi][0], sacc[mi][1], sacc[mi][2], sacc[mi][3]};
            *(f32x4*)(dst + mi * 16 + g * 4) = o;
        }
    }
}

// ---------------------------------------------------------------------------
// Final reduction over 64 partials + sum of b3.
// ---------------------------------------------------------------------------
__global__ __launch_bounds__(256) void reduce_out(const float* __restrict__ partial,
                                                  const float* __restrict__ b3,
                                                  float* __restrict__ out) {
    const int b = blockIdx.x * 256 + threadIdx.x;
    float v = 0.f;
#pragma unroll
    for (int p = 0; p < NPART; ++p) v += partial[(size_t)p * BATCH + b];
    float sb3 = 0.f;
#pragma unroll 4
    for (int f4 = 0; f4 < FDIM; f4 += 4) {
        const float4 t = *(const float4*)(b3 + f4);
        sb3 += t.x + t.y + t.z + t.w;
    }
    out[b] = v + sb3;
}

extern "C" void kernel_launch(void* const* d_in, const int* in_sizes, int n_in,
                              void* d_out, int out_size, void* d_ws, size_t ws_size,
                              hipStream_t stream) {
    const float* x  = (const float*)d_in[0];
    const float* W1 = (const float*)d_in[1];
    const float* b1 = (const float*)d_in[2];
    const float* W2 = (const float*)d_in[3];
    const float* b2 = (const float*)d_in[4];
    const float* W3 = (const float*)d_in[5];
    const float* b3 = (const float*)d_in[6];

    _Float16* w2f  = (_Float16*)d_ws;
    _Float16* xh   = w2f + W2F_HALVES;
    _Float16* w1b1 = xh + XH_HALVES;
    float* partial = (float*)(w1b1 + W1B1_HALVES);
    const size_t need = (W2F_HALVES + XH_HALVES + W1B1_HALVES) * sizeof(_Float16) +
                        (size_t)NPART * BATCH * sizeof(float);
    if (ws_size < need) return;  // insufficient scratch; fail visibly

    prep_all<<<2336, 256, 0, stream>>>(x, W1, b1, W2, w2f, xh, w1b1);
    coxnam_main<<<1024, 256, 0, stream>>>(xh, w1b1, w2f, b2, W3, partial);
    reduce_out<<<BATCH / 256, 256, 0, stream>>>(partial, b3, (float*)d_out);
}